// Round 14
// baseline (72.267 us; speedup 1.0000x reference)
//
#include <hip/hip_runtime.h>
#include <math.h>

// ---------------- problem constants ----------------
#define NROWS 4096
#define DIM   512
#define UNIT_I 128                 // grain i-rows
#define UNIT_J 64                  // grain j-rows
#define NGRAINS 1056               // sum_{p<32}(2p+2) = 8 * 132
#define KSTEPS (DIM / 32)          // 16 K-steps of 32
#define NSLOT 64                   // partial slots per row (direct+mirror, gap-free)

typedef __bf16 bf16x8 __attribute__((ext_vector_type(8)));
typedef float  f32x4  __attribute__((ext_vector_type(4)));

#define GL16(G, L) __builtin_amdgcn_global_load_lds( \
    (const __attribute__((address_space(1))) void*)(G), \
    (__attribute__((address_space(3))) void*)(L), 16, 0, 0)

// ---------------- kernel 1: row-normalize to bf16 (4 rows/block) ----------------
__global__ __launch_bounds__(256)
void normalize_kernel(const float* __restrict__ X, const float* __restrict__ Y,
                      __bf16* __restrict__ Xn, __bf16* __restrict__ Yn)
{
    const int wid  = threadIdx.x >> 6;
    const int lane = threadIdx.x & 63;
    const int row  = blockIdx.x * 4 + wid;
    const float* src = blockIdx.y ? Y : X;
    __bf16*      dst = blockIdx.y ? Yn : Xn;

    const float4* s4 = reinterpret_cast<const float4*>(src + (size_t)row * DIM);
    float4 v0 = s4[lane * 2 + 0];
    float4 v1 = s4[lane * 2 + 1];
    float ss = v0.x*v0.x + v0.y*v0.y + v0.z*v0.z + v0.w*v0.w
             + v1.x*v1.x + v1.y*v1.y + v1.z*v1.z + v1.w*v1.w;
    #pragma unroll
    for (int m = 1; m < 64; m <<= 1) ss += __shfl_xor(ss, m);
    const float scale = 1.0f / fmaxf(sqrtf(ss), 1e-8f);

    bf16x8 o;
    o[0] = (__bf16)(v0.x * scale); o[1] = (__bf16)(v0.y * scale);
    o[2] = (__bf16)(v0.z * scale); o[3] = (__bf16)(v0.w * scale);
    o[4] = (__bf16)(v1.x * scale); o[5] = (__bf16)(v1.y * scale);
    o[6] = (__bf16)(v1.z * scale); o[7] = (__bf16)(v1.w * scale);
    *reinterpret_cast<bf16x8*>(dst + (size_t)row * DIM + lane * 8) = o;
}

// ---------------- kernel 2: symmetric-triangle gram + exp-sum partials ----------------
// GRAIN (p, q): i-rows [128p, 128p+128), j-rows [64q, 64q+64), q in [0, 2p+2).
// 4 waves: m = wid>>1 (0=X/target, 1=Y/pred); iq = wid&1 (i-half of 64).
// WAVE-PRIVATE PIPELINE (R13->R14 change): each wave stages ITS OWN 64 j-rows
// and 64 i-rows of ITS matrix into PRIVATE LDS buffers via global_load_lds.
// Producer == consumer == same wave -> ZERO barriers in the K-loop; ordering is
// a per-wave counted s_waitcnt vmcnt(8) (stage s done, stage s+1 in flight --
// never drains to 0 mid-loop). Waves run as independent staggered pipelines.
// Wave computes C[j,i] = sum_k J[j,k]*I[i,k] over 64j x 64i (swapped operands:
// j lane-local; i = iq*64 + fi*16 + (lane&15)).
// Direct row-i sums -> slot q; mirror row-j sums -> slot (q>>1)+p+1 (skip when
// p == q>>1). Per row r: slots [0, (r>>7)+33) gap-free.
// Logits a=-simT, b=-simP in [-1,1] -> plain sums S,U,V,Q (no max tracking).
__global__ __launch_bounds__(256, 2)
void gram_kl_kernel(const __bf16* __restrict__ Xn, const __bf16* __restrict__ Yn,
                    float4* __restrict__ partials)
{
    // per wave: 2 stages x (J 4K | I 4K) = 16KB; 4 waves = 64KB -> 2 blocks/CU.
    // epilogue aliases [0,10K) after a full __syncthreads().
    __shared__ char lds[65536];

    const int tid  = threadIdx.x;
    const int wid  = tid >> 6;     // 0..3
    const int lane = tid & 63;
    const int m  = wid >> 1;       // matrix select (0=X/target, 1=Y/pred)
    const int iq = wid & 1;        // i-half

    // XCD-chunked map over 1056 = 8 * 132, then triangular decode
    const int gl = (blockIdx.x & 7) * (NGRAINS / 8) + (blockIdx.x >> 3);
    int p = (int)((sqrtf((float)(4 * gl + 1)) - 1.0f) * 0.5f);
    while ((p + 1) * (p + 2) <= gl) ++p;
    while (p * (p + 1) > gl) --p;
    const int q = gl - p * (p + 1);        // q in [0, 2p+2)
    const int i0 = p * UNIT_I;
    const int j0 = q * UNIT_J;
    const int diag = (p == (q >> 1));      // j-rows inside i-block -> no mirror

    // ---- per-lane pre-swizzled global source offsets ----
    // one GL16 covers 16 rows: lane u -> row (u>>2), LDS slot (u&3) holds
    // global seg (u&3) ^ ((row>>1)&3)
    const int xnib = (((lane & 3) ^ ((lane >> 3) & 3)) << 4);
    const int rr = lane >> 2;              // 0..15
    const size_t so_j = ((size_t)(j0 + rr) << 10) + xnib;
    const size_t so_i = ((size_t)(i0 + iq * 64 + rr) << 10) + xnib;

    const char* bx = (const char*)Xn;
    const char* srcM = m ? (const char*)Yn : bx;

    char* const wlds = &lds[wid * 16384];  // this wave's private region

    auto STAGE = [&](int st, int ks) {     // 8 GL16: J (4) + I (4)
        char* base = wlds + st * 8192;
        const size_t ko = (size_t)ks << 6;
        #pragma unroll
        for (int k2 = 0; k2 < 4; ++k2)     // rows 16*k2 .. 16*k2+15
            GL16(srcM + so_j + ((size_t)k2 << 14) + ko, base + k2 * 1024);
        #pragma unroll
        for (int k2 = 0; k2 < 4; ++k2)
            GL16(srcM + so_i + ((size_t)k2 << 14) + ko, base + 4096 + k2 * 1024);
    };

    // swizzled fragment read offset: row-part + xor'd 16B segment
    const int rdx = ((lane & 15) << 6) + ((((lane >> 4) ^ ((lane >> 1) & 3))) << 4);

    f32x4 acc[4][4];   // [fj][fi]
    #pragma unroll
    for (int fj = 0; fj < 4; ++fj)
        #pragma unroll
        for (int fi = 0; fi < 4; ++fi)
            acc[fj][fi] = f32x4{0.f, 0.f, 0.f, 0.f};

    STAGE(0, 0);

    for (int s = 0; s < KSTEPS; ++s) {
        if (s + 1 < KSTEPS) {
            STAGE((s + 1) & 1, s + 1);     // issue next stage first (stays in flight)
            asm volatile("s_waitcnt vmcnt(8)" ::: "memory");   // stage s complete
        } else {
            asm volatile("s_waitcnt vmcnt(0)" ::: "memory");
        }

        const char* base = wlds + (s & 1) * 8192;
        bf16x8 aJ[4], bI[4];
        #pragma unroll
        for (int fj = 0; fj < 4; ++fj)
            aJ[fj] = *reinterpret_cast<const bf16x8*>(base + fj * 1024 + rdx);
        #pragma unroll
        for (int fi = 0; fi < 4; ++fi)
            bI[fi] = *reinterpret_cast<const bf16x8*>(base + 4096 + fi * 1024 + rdx);

        __builtin_amdgcn_s_setprio(1);
        #pragma unroll
        for (int fj = 0; fj < 4; ++fj)
            #pragma unroll
            for (int fi = 0; fi < 4; ++fi)
                acc[fj][fi] = __builtin_amdgcn_mfma_f32_16x16x32_bf16(aJ[fj], bI[fi], acc[fj][fi], 0, 0, 0);
        __builtin_amdgcn_s_setprio(0);
    }

    // ---------------- chunked epilogue (register-lean, R11/R13-verified) ----------------
    // all waves done with private buffers after this barrier; alias scratch:
    // chunk [0,8K), jpart [8K,10K)
    char*  chunk = &lds[0];
    float* jpart = reinterpret_cast<float*>(&lds[8192]);  // [iq][64 j][4]

    const int sub = lane >> 4;
    float Si[4] = {0,0,0,0}, Ui[4] = {0,0,0,0}, Vi[4] = {0,0,0,0}, Qi[4] = {0,0,0,0};

    __syncthreads();

    #pragma unroll
    for (int fj = 0; fj < 4; ++fj) {
        if (m == 1) {   // P-waves dump this fj slice (8KB total)
            #pragma unroll
            for (int fi = 0; fi < 4; ++fi)
                *reinterpret_cast<f32x4*>(chunk + iq * 4096 + fi * 1024 + lane * 16) = acc[fj][fi];
        }
        __syncthreads();
        if (m == 0) {   // T-waves pair with matching P slice
            float js[4][4];
            #pragma unroll
            for (int r = 0; r < 4; ++r) { js[r][0]=0; js[r][1]=0; js[r][2]=0; js[r][3]=0; }
            #pragma unroll
            for (int fi = 0; fi < 4; ++fi) {
                const f32x4 pb = *reinterpret_cast<const f32x4*>(chunk + iq * 4096 + fi * 1024 + lane * 16);
                #pragma unroll
                for (int r = 0; r < 4; ++r) {
                    const float a = -acc[fj][fi][r];
                    const float b = -pb[r];
                    const float ea = __expf(a);
                    const float eb = __expf(b);
                    Si[fi] += ea; Ui[fi] += ea * a; Vi[fi] += ea * b; Qi[fi] += eb;
                    js[r][0] += ea; js[r][1] += ea * a; js[r][2] += ea * b; js[r][3] += eb;
                }
            }
            if (!diag) {   // mirror j-sums: reduce over the 16 i-lanes
                #pragma unroll
                for (int r = 0; r < 4; ++r)
                    #pragma unroll
                    for (int c = 0; c < 4; ++c) {
                        #pragma unroll
                        for (int mk = 1; mk <= 8; mk <<= 1)
                            js[r][c] += __shfl_xor(js[r][c], mk);
                    }
                if ((lane & 15) == 0) {
                    #pragma unroll
                    for (int r = 0; r < 4; ++r) {
                        const int j = fj * 16 + sub * 4 + r;
                        #pragma unroll
                        for (int c = 0; c < 4; ++c)
                            jpart[(iq * 64 + j) * 4 + c] = js[r][c];
                    }
                }
            }
        }
        __syncthreads();
    }

    // direct row-i sums: reduce across the 4 j-subgroups, write slot q
    if (m == 0) {
        #pragma unroll
        for (int fi = 0; fi < 4; ++fi) {
            #pragma unroll
            for (int mk = 16; mk <= 32; mk <<= 1) {
                Si[fi] += __shfl_xor(Si[fi], mk);
                Ui[fi] += __shfl_xor(Ui[fi], mk);
                Vi[fi] += __shfl_xor(Vi[fi], mk);
                Qi[fi] += __shfl_xor(Qi[fi], mk);
            }
        }
        if (lane < 16) {
            #pragma unroll
            for (int fi = 0; fi < 4; ++fi) {
                const int row = i0 + iq * 64 + fi * 16 + lane;
                partials[(size_t)row * NSLOT + q] = float4{Si[fi], Ui[fi], Vi[fi], Qi[fi]};
            }
        }
    }
    __syncthreads();

    // mirror combine across iq halves, write slot (q>>1)+p+1 (off-diagonal only)
    if (!diag && wid == 0) {
        const int j = lane;   // 0..63
        const int mslot = (q >> 1) + p + 1;
        float4 v;
        v.x = jpart[(0 * 64 + j) * 4 + 0] + jpart[(1 * 64 + j) * 4 + 0];
        v.y = jpart[(0 * 64 + j) * 4 + 1] + jpart[(1 * 64 + j) * 4 + 1];
        v.z = jpart[(0 * 64 + j) * 4 + 2] + jpart[(1 * 64 + j) * 4 + 2];
        v.w = jpart[(0 * 64 + j) * 4 + 3] + jpart[(1 * 64 + j) * 4 + 3];
        partials[(size_t)(j0 + j) * NSLOT + mslot] = v;
    }
}

// ---------------- kernel 3: merge partial sums -> per-row KL, block-reduce ----------------
// Row r uses slots [0, (r>>7)+33): direct [0, 2*(r>>7)+2) + mirror [.., (r>>7)+33).
__global__ __launch_bounds__(256)
void merge_kernel(const float4* __restrict__ partials, float* __restrict__ blocksum)
{
    __shared__ float w[4];
    const int row = blockIdx.x * 256 + threadIdx.x;
    const int nsl = (row >> 7) + 33;
    float S = 0.f, U = 0.f, V = 0.f, Q = 0.f;
    for (int s = 0; s < nsl; ++s) {
        const float4 pp = partials[(size_t)row * NSLOT + s];
        S += pp.x; U += pp.y; V += pp.z; Q += pp.w;
    }
    float kl = (U - V) / S - logf(S) + logf(Q);
    #pragma unroll
    for (int mm = 1; mm < 64; mm <<= 1) kl += __shfl_xor(kl, mm);
    if ((threadIdx.x & 63) == 0) w[threadIdx.x >> 6] = kl;
    __syncthreads();
    if (threadIdx.x == 0) blocksum[blockIdx.x] = w[0] + w[1] + w[2] + w[3];
}

// ---------------- kernel 4: final mean ----------------
__global__ __launch_bounds__(64)
void reduce_kernel(const float* __restrict__ blocksum, float* __restrict__ out)
{
    float v = (threadIdx.x < 16) ? blocksum[threadIdx.x] : 0.f;
    #pragma unroll
    for (int mm = 1; mm < 16; mm <<= 1) v += __shfl_xor(v, mm);
    if (threadIdx.x == 0) out[0] = v / (float)NROWS;
}

// ---------------- launch ----------------
extern "C" void kernel_launch(void* const* d_in, const int* in_sizes, int n_in,
                              void* d_out, int out_size, void* d_ws, size_t ws_size,
                              hipStream_t stream)
{
    const float* X = (const float*)d_in[0];   // cosine_distance_latent (target)
    const float* Y = (const float*)d_in[1];   // mse_latent (predicted)
    float* out = (float*)d_out;

    char* ws = (char*)d_ws;
    const size_t mat_bytes = (size_t)NROWS * DIM * sizeof(__bf16);          // 4 MiB each
    __bf16* Xn = (__bf16*)ws;
    __bf16* Yn = (__bf16*)(ws + mat_bytes);
    float4* partials = (float4*)(ws + 2 * mat_bytes);                       // 4096*64*16 B = 4 MiB
    float* blocksum = (float*)(ws + 2 * mat_bytes + (size_t)NROWS * NSLOT * sizeof(float4));

    normalize_kernel<<<dim3(NROWS / 4, 2), 256, 0, stream>>>(X, Y, Xn, Yn);
    gram_kl_kernel<<<NGRAINS, 256, 0, stream>>>(Xn, Yn, partials);
    merge_kernel<<<NROWS / 256, 256, 0, stream>>>(partials, blocksum);
    reduce_kernel<<<1, 64, 0, stream>>>(blocksum, out);
}